// Round 15
// baseline (3332.802 us; speedup 1.0000x reference)
//
#include <hip/hip_runtime.h>

#define T_STEPS 512
#define BB 64
#define EE 300
#define EP 320
#define HH 512
#define HB (BB*HH)        // halves per h slot (65536 B)
#define XPSLOT 524288     // bytes per xp slot: 64 rows * 512 cols * 16B (f32 r,z,n,pad)
#define FS 16             // flag stride in ints (64 B): producer-exclusive cache line

typedef _Float16 f16x8 __attribute__((ext_vector_type(8)));
typedef float f32x4 __attribute__((ext_vector_type(4)));
typedef int i32x4 __attribute__((ext_vector_type(4)));

__device__ __forceinline__ f32x4 mf(f16x8 a, f16x8 b, f32x4 c) {
  return __builtin_amdgcn_mfma_f32_16x16x32_f16(a, b, c, 0, 0, 0);
}

// ---- 4-phase progressive split-K load blocks (write-once h -> PLAIN loads) ----
// Producer sets {0-3}/{4-11}/{12-31} own chunks {0-1}/{2-5}/{6-15}. Lead wait is
// max-over-4 only; each later set's readiness is probed via one sc1 flag load
// riding the PREVIOUS data drain and checked from registers (flags monotone, so a
// stale "ready" is still valid). Fallback polls only when a probe misses.

// Drain A: chunks 0-1 + 4 sc1 xp loads + probe(producers 4-11), ONE drain.
__device__ __forceinline__ void load_h2a_xp_probe(i32x4* q, f32x4* xp, int* pb,
    const void* hbase, int hvoff, const void* xbase, const int* vx,
    const int* probe) {
  asm volatile(
    "global_load_dwordx4 %0, %7,  %8\n\t"
    "global_load_dwordx4 %1, %7,  %8 offset:64\n\t"
    "global_load_dwordx4 %2, %9,  %13 sc1\n\t"
    "global_load_dwordx4 %3, %10, %13 sc1\n\t"
    "global_load_dwordx4 %4, %11, %13 sc1\n\t"
    "global_load_dwordx4 %5, %12, %13 sc1\n\t"
    "global_load_dword   %6, %14, off sc1\n\t"
    "s_waitcnt vmcnt(0)"
    : "=v"(q[0]), "=v"(q[1]),
      "=v"(xp[0]), "=v"(xp[1]), "=v"(xp[2]), "=v"(xp[3]), "=v"(*pb)
    : "v"(hvoff), "s"(hbase), "v"(vx[0]), "v"(vx[1]), "v"(vx[2]), "v"(vx[3]),
      "s"(xbase), "v"(probe)
    : "memory");
}

// Drain A for P1: chunks 0-1 + probe(4-11), one drain
__device__ __forceinline__ void load_h2a_probe(i32x4* q, int* pb,
    const void* hbase, int hvoff, const int* probe) {
  asm volatile(
    "global_load_dwordx4 %0, %3, %4\n\t"
    "global_load_dwordx4 %1, %3, %4 offset:64\n\t"
    "global_load_dword   %2, %5, off sc1\n\t"
    "s_waitcnt vmcnt(0)"
    : "=v"(q[0]), "=v"(q[1]), "=v"(*pb)
    : "v"(hvoff), "s"(hbase), "v"(probe) : "memory");
}

// Drain B: chunks 2-5 (producers 4-11) + probe(12-31), one drain
__device__ __forceinline__ void load_h4b_probe(i32x4* q, int* pc,
    const void* hbase, int hvoff, const int* probe) {
  asm volatile(
    "global_load_dwordx4 %0, %5, %6 offset:128\n\t"
    "global_load_dwordx4 %1, %5, %6 offset:192\n\t"
    "global_load_dwordx4 %2, %5, %6 offset:256\n\t"
    "global_load_dwordx4 %3, %5, %6 offset:320\n\t"
    "global_load_dword   %4, %7, off sc1\n\t"
    "s_waitcnt vmcnt(0)"
    : "=v"(q[0]), "=v"(q[1]), "=v"(q[2]), "=v"(q[3]), "=v"(*pc)
    : "v"(hvoff), "s"(hbase), "v"(probe) : "memory");
}

// Drain C: chunks 6-15 (producers 12-31), one drain (10 loads)
__device__ __forceinline__ void load_h10c(i32x4* q, const void* hbase, int hvoff) {
  asm volatile(
    "global_load_dwordx4 %0, %10, %11 offset:384\n\t"
    "global_load_dwordx4 %1, %10, %11 offset:448\n\t"
    "global_load_dwordx4 %2, %10, %11 offset:512\n\t"
    "global_load_dwordx4 %3, %10, %11 offset:576\n\t"
    "global_load_dwordx4 %4, %10, %11 offset:640\n\t"
    "global_load_dwordx4 %5, %10, %11 offset:704\n\t"
    "global_load_dwordx4 %6, %10, %11 offset:768\n\t"
    "global_load_dwordx4 %7, %10, %11 offset:832\n\t"
    "global_load_dwordx4 %8, %10, %11 offset:896\n\t"
    "global_load_dwordx4 %9, %10, %11 offset:960\n\t"
    "s_waitcnt vmcnt(0)"
    : "=v"(q[0]), "=v"(q[1]), "=v"(q[2]), "=v"(q[3]), "=v"(q[4]),
      "=v"(q[5]), "=v"(q[6]), "=v"(q[7]), "=v"(q[8]), "=v"(q[9])
    : "v"(hvoff), "s"(hbase) : "memory");
}

__device__ __forceinline__ void load_xp4(f32x4* xp, const void* xbase, const int* vx) {
  asm volatile(
    "global_load_dwordx4 %0, %4, %8 sc1\n\t"
    "global_load_dwordx4 %1, %5, %8 sc1\n\t"
    "global_load_dwordx4 %2, %6, %8 sc1\n\t"
    "global_load_dwordx4 %3, %7, %8 sc1\n\t"
    "s_waitcnt vmcnt(0)"
    : "=v"(xp[0]), "=v"(xp[1]), "=v"(xp[2]), "=v"(xp[3])
    : "v"(vx[0]), "v"(vx[1]), "v"(vx[2]), "v"(vx[3]), "s"(xbase) : "memory");
}

// batched x-prefetch: 10 plain cached loads + full drain (x0 is immutable)
__device__ __forceinline__ void loadx10_wait(i32x4* xq, const void* base, int voff) {
  asm volatile(
    "global_load_dwordx4 %0, %10, %11\n\t"
    "global_load_dwordx4 %1, %10, %11 offset:64\n\t"
    "global_load_dwordx4 %2, %10, %11 offset:128\n\t"
    "global_load_dwordx4 %3, %10, %11 offset:192\n\t"
    "global_load_dwordx4 %4, %10, %11 offset:256\n\t"
    "global_load_dwordx4 %5, %10, %11 offset:320\n\t"
    "global_load_dwordx4 %6, %10, %11 offset:384\n\t"
    "global_load_dwordx4 %7, %10, %11 offset:448\n\t"
    "global_load_dwordx4 %8, %10, %11 offset:512\n\t"
    "global_load_dwordx4 %9, %10, %11 offset:576\n\t"
    "s_waitcnt vmcnt(0)"
    : "=v"(xq[0]), "=v"(xq[1]), "=v"(xq[2]), "=v"(xq[3]), "=v"(xq[4]),
      "=v"(xq[5]), "=v"(xq[6]), "=v"(xq[7]), "=v"(xq[8]), "=v"(xq[9])
    : "v"(voff), "s"(base) : "memory");
}

__device__ __forceinline__ f16x8 fragq(i32x4 q) {
  union { i32x4 i; f16x8 v; } x; x.i = q; return x.v;
}

// publish: write-through to MALL (no L2 allocate) so consumers' L2 fills are fresh
__device__ __forceinline__ void st16_mall(void* p, f16x8 v) {
  i32x4 iv;
  __builtin_memcpy(&iv, &v, 16);
  asm volatile("global_store_dwordx4 %0, %1, off sc0 sc1" :: "v"(p), "v"(iv) : "memory");
}
__device__ __forceinline__ void st16f(void* p, f32x4 v) {
  i32x4 iv;
  __builtin_memcpy(&iv, &v, 16);
  asm volatile("global_store_dwordx4 %0, %1, off sc0 sc1" :: "v"(p), "v"(iv) : "memory");
}
__device__ __forceinline__ void st4_dev(int* p, int v) {
  asm volatile("global_store_dword %0, %1, off sc0 sc1" :: "v"(p), "v"(v) : "memory");
}

// leading wait: lanes 0-31 poll the 4 phase-A producer lines (8 dup lanes each),
// lanes 32-63 poll ONE column-matched xp flag (broadcast-coalesced).
__device__ __forceinline__ void wait4_plus1(const int* b4, int t4,
                                            const int* pone, int tone, int slp) {
  const int lane = threadIdx.x & 63;
  const int* p = (lane < 32) ? (b4 + (lane & 3) * FS) : pone;
  const int t = (lane < 32) ? t4 : tone;
  for (;;) {
    int v;
    asm volatile("global_load_dword %0, %1, off sc1\n\ts_waitcnt vmcnt(0)"
                 : "=v"(v) : "v"(p) : "memory");
    if (__all(v >= t)) return;
    for (int i = 0; i < slp; ++i) __builtin_amdgcn_s_sleep(1);
  }
}

// fallback waits when an optimistic probe missed (rare)
__device__ __forceinline__ void wait8set(const int* base, int t, int slp) {
  const int* p = base + (threadIdx.x & 7) * FS;    // producers base..base+7
  for (;;) {
    int v;
    asm volatile("global_load_dword %0, %1, off sc1\n\ts_waitcnt vmcnt(0)"
                 : "=v"(v) : "v"(p) : "memory");
    if (__all(v >= t)) return;
    for (int i = 0; i < slp; ++i) __builtin_amdgcn_s_sleep(1);
  }
}
__device__ __forceinline__ void wait20(const int* fg, int t, int slp) {
  const int lane = threadIdx.x & 63;
  const int* p = fg + (12 + (lane % 20)) * FS;     // producers 12-31
  for (;;) {
    int v;
    asm volatile("global_load_dword %0, %1, off sc1\n\ts_waitcnt vmcnt(0)"
                 : "=v"(v) : "v"(p) : "memory");
    if (__all(v >= t)) return;
    for (int i = 0; i < slp; ++i) __builtin_amdgcn_s_sleep(1);
  }
}

// single-flag wait (all lanes broadcast-load one address)
__device__ __forceinline__ void wait_one(const int* p, int t, int slp) {
  for (;;) {
    int v;
    asm volatile("global_load_dword %0, %1, off sc1\n\ts_waitcnt vmcnt(0)"
                 : "=v"(v) : "v"(p) : "memory");
    if (__all(v >= t)) return;
    for (int i = 0; i < slp; ++i) __builtin_amdgcn_s_sleep(1);
  }
}

__device__ __forceinline__ float sigf(float x) { return 1.f / (1.f + __expf(-x)); }

struct B3 { f16x8 r, z, n; };
// LDS weight read: [chunk][gate(3)][jj(16)][40 halves] — 40-half jj stride spreads the
// 16 cols across bank windows 4*((5*jj+quad) mod 8): uniform, max 2-way (free).
__device__ __forceinline__ B3 ldsB(const _Float16* wl, int chunk, int jj, int kq) {
  B3 o;
  const _Float16* p = wl + chunk * 1920 + jj * 40 + kq;
  o.r = *(const f16x8*)p;
  o.z = *(const f16x8*)(p + 640);
  o.n = *(const f16x8*)(p + 1280);
  return o;
}

__global__ void prep_x0(const int* __restrict__ texts, const float* __restrict__ emb,
                        _Float16* __restrict__ x0) {
  const size_t N = (size_t)T_STEPS * BB * EP;
  const size_t stride = (size_t)gridDim.x * blockDim.x;
  for (size_t i = (size_t)blockIdx.x * blockDim.x + threadIdx.x; i < N; i += stride) {
    int e = (int)(i % EP);
    size_t tb = i / EP;
    float v = 0.f;
    if (e < EE) v = emb[(size_t)texts[tb] * EE + e];
    x0[i] = (_Float16)v;
  }
}

__global__ void prep_b(const float* __restrict__ bih0, const float* __restrict__ bhh0,
                       const float* __restrict__ bih1, const float* __restrict__ bhh1,
                       float* __restrict__ bias0, float* __restrict__ bias1) {
  int i = blockIdx.x * blockDim.x + threadIdx.x;
  if (i < HH) {
    bias0[i]        = bih0[i] + bhh0[i];
    bias0[512 + i]  = bih0[512 + i] + bhh0[512 + i];
    bias0[1024 + i] = bih0[1024 + i];
    bias0[1536 + i] = bhh0[1024 + i];
    bias1[i]        = bih1[i] + bhh1[i];
    bias1[512 + i]  = bih1[512 + i] + bhh1[512 + i];
    bias1[1024 + i] = bih1[1024 + i];
    bias1[1536 + i] = bhh1[1024 + i];
  }
}

// 128 WGs x 256 threads, 4 roles x 32 WGs; each WG = 4 independent waves, one per
// 16-row batch group. 4-PHASE PROGRESSIVE split-K detect: lead wait on producers
// 0-3 only (max4) + xp flag; sets {4-11} and {12-31} probed via flag loads riding
// the previous data drains, checked from registers — tails hide behind accumulated
// load+MFMA cover. h1/h2 WRITE-ONCE (plain cached loads); xp rings sc1 with
// column-matched single-flag deps; pooled partials are plain stores.
__global__ __launch_bounds__(256, 1) void gru_persistent(
    const _Float16* __restrict__ x0,
    const float* __restrict__ Wih0, const float* __restrict__ Whh0,
    const float* __restrict__ Wih1, const float* __restrict__ Whh1,
    const float* __restrict__ bias0, const float* __restrict__ bias1,
    _Float16* h1seq, _Float16* h2seq, float* xp0ring, float* xp1ring,
    float* pooledPart, int* flags0, int* flagsP0, int* flagsP1, int* flags1)
{
  const int wg   = blockIdx.x;
  const int role = wg >> 5;          // 0=L0 1=P0 2=P1 3=L1
  const int w    = wg & 31;          // column slice 0..31
  const int jb   = w * 16;           // 16 h-cols per WG
  const int tid  = threadIdx.x;
  const int g    = tid >> 6;         // wave = batch group, rows g*16..+15
  const int lane = tid & 63;
  const int quad = lane >> 4;
  const int l15  = lane & 15;
  const int kq   = quad * 8;
  const int hoff = (g * 16 + l15) * 1024 + quad * 16;  // byte voffset into an h slot

  __shared__ alignas(16) _Float16 wlds[30720];     // 16 chunks x 1920 halves = 60 KiB
  __shared__ alignas(16) _Float16 tile[4][16][16]; // per-wave publish transpose, 2 KiB

  // ---- one-time LDS weight fill (fp32 global -> f16, 40-half jj stride) ----
  {
    const float* Wsrc = (role == 0) ? Whh0 : (role == 1) ? Wih0
                      : (role == 2) ? Wih1 : Whh1;
    const int nch  = (role == 1) ? 10 : 16;
    const int Ksrc = (role == 1) ? EE : HH;
    for (int idx = tid; idx < nch * 192; idx += 256) {
      int q = idx & 3, jj = (idx >> 2) & 15, g3 = (idx >> 6) % 3, ch = idx / 192;
      int row = g3 * 512 + jb + jj;
      _Float16* dst = wlds + ch * 1920 + g3 * 640 + jj * 40 + q * 8;
      int colb = ch * 32 + q * 8;
      #pragma unroll
      for (int e = 0; e < 8; ++e) {
        int col = colb + e;
        dst[e] = (col < Ksrc) ? (_Float16)Wsrc[(size_t)row * Ksrc + col] : (_Float16)0.f;
      }
    }
  }
  __syncthreads();

  // loop-invariant xp voffsets: [row 64][hcol 512][gate pad4] f32 -> row stride 8192 B
  int vx[4];
  #pragma unroll
  for (int rg = 0; rg < 4; ++rg)
    vx[rg] = (g * 16 + quad * 4 + rg) * 8192 + (jb + l15) * 16;

  const int* fg0  = flags0  + g * 32 * FS;   // 32 producers x 64B per group
  const int* fgP0 = flagsP0 + g * 32 * FS;
  const int* fgP1 = flagsP1 + g * 32 * FS;
  const int* fg1  = flags1  + g * 32 * FS;
  const int  pB   = (4 + (lane & 7)) * FS;    // probe offset: producers 4-11
  const int  pC   = (12 + (lane % 20)) * FS;  // probe offset: producers 12-31

  if (role == 0) {            // ---------------- L0: h1 recurrence ----------------
    const int j = jb + l15;
    const float br = bias0[j], bz = bias0[512 + j];
    const float bnx = bias0[1024 + j], bnh = bias0[1536 + j];
    int* myf = flags0 + (g * 32 + w) * FS;
    const int* pP0w = fgP0 + w * FS;           // single column-matched P0 flag
    const int* prbB = fg0 + pB;
    const int* prbC = fg0 + pC;
    float hprev[4] = {0.f, 0.f, 0.f, 0.f};
    _Float16 (*tc)[16] = tile[g];
    for (int s = 0; s < T_STEPS; ++s) {
      // phase-A h dep (producers 0-3) + xp dep (P0 WG w only)
      wait4_plus1(fg0, s, pP0w, s + 1, 1);
      f32x4 hR = {0.f,0.f,0.f,0.f}, hZ = {0.f,0.f,0.f,0.f}, hN = {0.f,0.f,0.f,0.f};
      f32x4 xp[4];
      const void* xb = (const char*)xp0ring + (size_t)(s & 15) * XPSLOT;
      if (s >= 1) {
        const void* hb = h1seq + (size_t)(s - 1) * HB;
        i32x4 qa[2]; int pb;
        load_h2a_xp_probe(qa, xp, &pb, hb, hoff, xb, vx, prbB);
        #pragma unroll
        for (int c = 0; c < 2; ++c) {
          f16x8 a = fragq(qa[c]);
          B3 bb = ldsB(wlds, c, l15, kq);
          hR = mf(a, bb.r, hR); hZ = mf(a, bb.z, hZ); hN = mf(a, bb.n, hN);
        }
        if (!__all(pb >= s)) wait8set(fg0 + 4 * FS, s, 1);
        i32x4 qb[4]; int pc;
        load_h4b_probe(qb, &pc, hb, hoff, prbC);
        #pragma unroll
        for (int c = 0; c < 4; ++c) {
          f16x8 a = fragq(qb[c]);
          B3 bb = ldsB(wlds, 2 + c, l15, kq);
          hR = mf(a, bb.r, hR); hZ = mf(a, bb.z, hZ); hN = mf(a, bb.n, hN);
        }
        if (!__all(pc >= s)) wait20(fg0, s, 1);
        i32x4 qc[10];
        load_h10c(qc, hb, hoff);
        #pragma unroll 5
        for (int c = 0; c < 10; ++c) {
          f16x8 a = fragq(qc[c]);
          B3 bb = ldsB(wlds, 6 + c, l15, kq);
          hR = mf(a, bb.r, hR); hZ = mf(a, bb.z, hZ); hN = mf(a, bb.n, hN);
        }
      } else {
        load_xp4(xp, xb, vx);
      }
      #pragma unroll
      for (int rg = 0; rg < 4; ++rg) {
        float r = sigf(xp[rg][0] + hR[rg] + br);
        float z = sigf(xp[rg][1] + hZ[rg] + bz);
        float n = tanhf(xp[rg][2] + bnx + r * (hN[rg] + bnh));
        float hnew = (1.f - z) * n + z * hprev[rg];
        hprev[rg] = hnew;
        tc[quad * 4 + rg][l15] = (_Float16)hnew;
      }
      if (lane < 32) {                      // 16 rows x 32B per wave
        int row = lane & 15, hb2 = lane >> 4;
        f16x8 v = *(const f16x8*)&tc[row][hb2 * 8];
        st16_mall(h1seq + (size_t)s * HB
                  + (size_t)(g * 16 + row) * HH + jb + hb2 * 8, v);
      }
      __builtin_amdgcn_s_waitcnt(0);
      if (lane == 0) st4_dev(myf, s + 1);
    }
  } else if (role == 1) {     // ---------------- P0: x projection (ahead) ----------------
    int* myf = flagsP0 + (g * 32 + w) * FS;
    const int* pL0w = fg0 + w * FS;            // only L0 WG w consumes our slice
    const int xoff = (g * 16 + l15) * 640 + quad * 16;
    for (int t = 0; t < T_STEPS; ++t) {
      wait_one(pL0w, t - 15, 8);               // ring throttle — slack, slow sampling
      i32x4 xq[10];
      loadx10_wait(xq, x0 + (size_t)t * BB * EP, xoff);
      f32x4 aR = {0.f,0.f,0.f,0.f}, aZ = {0.f,0.f,0.f,0.f}, aN = {0.f,0.f,0.f,0.f};
      #pragma unroll 5
      for (int c = 0; c < 10; ++c) {
        f16x8 a = fragq(xq[c]);
        B3 bb = ldsB(wlds, c, l15, kq);
        aR = mf(a, bb.r, aR); aZ = mf(a, bb.z, aZ); aN = mf(a, bb.n, aN);
      }
      char* xb = (char*)xp0ring + (size_t)(t & 15) * XPSLOT;
      #pragma unroll
      for (int rg = 0; rg < 4; ++rg) {
        f32x4 v = {aR[rg], aZ[rg], aN[rg], 0.f};
        st16f(xb + vx[rg], v);
      }
      __builtin_amdgcn_s_waitcnt(0);
      if (lane == 0) st4_dev(myf, t + 1);
    }
  } else if (role == 2) {     // ---------------- P1: h1 -> xp1 projection ----------------
    int* myf = flagsP1 + (g * 32 + w) * FS;
    const int* pL1w = fg1 + w * FS;            // only L1 WG w consumes our slice
    const int* prbB = fg0 + pB;
    const int* prbC = fg0 + pC;
    for (int t = 0; t < T_STEPS; ++t) {
      // phase-A of h1[t] (producers 0-3 >= t+1); ring throttle single L1 flag
      wait4_plus1(fg0, t + 1, pL1w, t - 3, 1);
      const void* hb = h1seq + (size_t)t * HB;
      i32x4 qa[2]; int pb;
      load_h2a_probe(qa, &pb, hb, hoff, prbB);
      f32x4 aR = {0.f,0.f,0.f,0.f}, aZ = {0.f,0.f,0.f,0.f}, aN = {0.f,0.f,0.f,0.f};
      #pragma unroll
      for (int c = 0; c < 2; ++c) {
        f16x8 a = fragq(qa[c]);
        B3 bb = ldsB(wlds, c, l15, kq);
        aR = mf(a, bb.r, aR); aZ = mf(a, bb.z, aZ); aN = mf(a, bb.n, aN);
      }
      if (!__all(pb >= t + 1)) wait8set(fg0 + 4 * FS, t + 1, 1);
      i32x4 qb[4]; int pc;
      load_h4b_probe(qb, &pc, hb, hoff, prbC);
      #pragma unroll
      for (int c = 0; c < 4; ++c) {
        f16x8 a = fragq(qb[c]);
        B3 bb = ldsB(wlds, 2 + c, l15, kq);
        aR = mf(a, bb.r, aR); aZ = mf(a, bb.z, aZ); aN = mf(a, bb.n, aN);
      }
      if (!__all(pc >= t + 1)) wait20(fg0, t + 1, 1);
      i32x4 qc[10];
      load_h10c(qc, hb, hoff);
      #pragma unroll 5
      for (int c = 0; c < 10; ++c) {
        f16x8 a = fragq(qc[c]);
        B3 bb = ldsB(wlds, 6 + c, l15, kq);
        aR = mf(a, bb.r, aR); aZ = mf(a, bb.z, aZ); aN = mf(a, bb.n, aN);
      }
      char* xb = (char*)xp1ring + (size_t)(t & 3) * XPSLOT;
      #pragma unroll
      for (int rg = 0; rg < 4; ++rg) {
        f32x4 v = {aR[rg], aZ[rg], aN[rg], 0.f};
        st16f(xb + vx[rg], v);
      }
      __builtin_amdgcn_s_waitcnt(0);
      if (lane == 0) st4_dev(myf, t + 1);
    }
  } else {                    // ---------------- L1: h2 recurrence ----------------
    const int j = jb + l15;
    const float br = bias1[j], bz = bias1[512 + j];
    const float bnx = bias1[1024 + j], bnh = bias1[1536 + j];
    int* myf = flags1 + (g * 32 + w) * FS;
    const int* pP1w = fgP1 + w * FS;           // single column-matched P1 flag
    const int* prbB = fg1 + pB;
    const int* prbC = fg1 + pC;
    float* ppB = pooledPart + ((size_t)g * T_STEPS) * HH + jb;
    float hprev[4] = {0.f, 0.f, 0.f, 0.f};
    _Float16 (*tc)[16] = tile[g];
    for (int t = 0; t < T_STEPS; ++t) {
      // phase-A h dep (producers 0-3 >= t) + xp dep (P1 WG w only >= t+1)
      wait4_plus1(fg1, t, pP1w, t + 1, 1);
      f32x4 hR = {0.f,0.f,0.f,0.f}, hZ = {0.f,0.f,0.f,0.f}, hN = {0.f,0.f,0.f,0.f};
      f32x4 xp[4];
      const void* xb = (const char*)xp1ring + (size_t)(t & 3) * XPSLOT;
      if (t >= 1) {
        const void* hb = h2seq + (size_t)(t - 1) * HB;
        i32x4 qa[2]; int pb;
        load_h2a_xp_probe(qa, xp, &pb, hb, hoff, xb, vx, prbB);
        #pragma unroll
        for (int c = 0; c < 2; ++c) {
          f16x8 a = fragq(qa[c]);
          B3 bb = ldsB(wlds, c, l15, kq);
          hR = mf(a, bb.r, hR); hZ = mf(a, bb.z, hZ); hN = mf(a, bb.n, hN);
        }
        if (!__all(pb >= t)) wait8set(fg1 + 4 * FS, t, 1);
        i32x4 qb[4]; int pc;
        load_h4b_probe(qb, &pc, hb, hoff, prbC);
        #pragma unroll
        for (int c = 0; c < 4; ++c) {
          f16x8 a = fragq(qb[c]);
          B3 bb = ldsB(wlds, 2 + c, l15, kq);
          hR = mf(a, bb.r, hR); hZ = mf(a, bb.z, hZ); hN = mf(a, bb.n, hN);
        }
        if (!__all(pc >= t)) wait20(fg1, t, 1);
        i32x4 qc[10];
        load_h10c(qc, hb, hoff);
        #pragma unroll 5
        for (int c = 0; c < 10; ++c) {
          f16x8 a = fragq(qc[c]);
          B3 bb = ldsB(wlds, 6 + c, l15, kq);
          hR = mf(a, bb.r, hR); hZ = mf(a, bb.z, hZ); hN = mf(a, bb.n, hN);
        }
      } else {
        load_xp4(xp, xb, vx);
      }
      #pragma unroll
      for (int rg = 0; rg < 4; ++rg) {
        float r = sigf(xp[rg][0] + hR[rg] + br);
        float z = sigf(xp[rg][1] + hZ[rg] + bz);
        float n = tanhf(xp[rg][2] + bnx + r * (hN[rg] + bnh));
        float hnew = (1.f - z) * n + z * hprev[rg];
        hprev[rg] = hnew;
        tc[quad * 4 + rg][l15] = (_Float16)hnew;
      }
      if (lane < 32) {
        int row = lane & 15, hb2 = lane >> 4;
        f16x8 v = *(const f16x8*)&tc[row][hb2 * 8];
        st16_mall(h2seq + (size_t)t * HB
                  + (size_t)(g * 16 + row) * HH + jb + hb2 * 8, v);
      }
      __builtin_amdgcn_s_waitcnt(0);
      if (lane == 0) st4_dev(myf, t + 1);
      // tail (off the flag path): per-group pooled partial, PLAIN store (write-once)
      if (lane < 16) {
        float sum = 0.f;
        #pragma unroll
        for (int r = 0; r < 16; ++r) sum += (float)tc[r][lane];
        ppB[(size_t)t * HH + lane] = sum;
      }
    }
  }
}

__global__ void fc_kernel(const float* __restrict__ pooledPart,
                          const float* __restrict__ fcW,
                          const float* __restrict__ fcb, float* __restrict__ out) {
  const int t = blockIdx.x;
  const int lane = threadIdx.x;  // 64 = one wave
  const size_t GS = (size_t)T_STEPS * HH;   // per-group partial stride
  float a0 = 0.f, a1 = 0.f, a2 = 0.f, a3 = 0.f, a4 = 0.f;
  for (int jj = lane; jj < HH; jj += 64) {
    size_t idx = (size_t)t * HH + jj;
    float p = pooledPart[idx] + pooledPart[GS + idx]
            + pooledPart[2 * GS + idx] + pooledPart[3 * GS + idx];
    a0 += p * fcW[jj];
    a1 += p * fcW[512 + jj];
    a2 += p * fcW[1024 + jj];
    a3 += p * fcW[1536 + jj];
    a4 += p * fcW[2048 + jj];
  }
  #pragma unroll
  for (int off = 32; off > 0; off >>= 1) {
    a0 += __shfl_down(a0, off, 64);
    a1 += __shfl_down(a1, off, 64);
    a2 += __shfl_down(a2, off, 64);
    a3 += __shfl_down(a3, off, 64);
    a4 += __shfl_down(a4, off, 64);
  }
  if (lane == 0) {
    const float sc = 1.f / 64.f;
    out[t * 5 + 0] = a0 * sc + fcb[0];
    out[t * 5 + 1] = a1 * sc + fcb[1];
    out[t * 5 + 2] = a2 * sc + fcb[2];
    out[t * 5 + 3] = a3 * sc + fcb[3];
    out[t * 5 + 4] = a4 * sc + fcb[4];
  }
}

extern "C" void kernel_launch(void* const* d_in, const int* in_sizes, int n_in,
                              void* d_out, int out_size, void* d_ws, size_t ws_size,
                              hipStream_t stream) {
  const int*   texts = (const int*)  d_in[0];
  const float* emb   = (const float*)d_in[1];
  const float* Wih0  = (const float*)d_in[2];
  const float* Whh0  = (const float*)d_in[3];
  const float* bih0  = (const float*)d_in[4];
  const float* bhh0  = (const float*)d_in[5];
  const float* Wih1  = (const float*)d_in[6];
  const float* Whh1  = (const float*)d_in[7];
  const float* bih1  = (const float*)d_in[8];
  const float* bhh1  = (const float*)d_in[9];
  const float* fcW   = (const float*)d_in[10];
  const float* fcb   = (const float*)d_in[11];
  float* out = (float*)d_out;

  char* ws = (char*)d_ws;
  int*      flags0   = (int*)ws;                     // 8192 B (4 grp x 32 x 64B)
  int*      flagsP0  = (int*)(ws + 8192);            // 8192 B
  int*      flagsP1  = (int*)(ws + 16384);           // 8192 B
  int*      flags1   = (int*)(ws + 24576);           // 8192 B
  float*    pooledPt = (float*)(ws + 32768);         // 4194304 B [4][512][512] f32
  _Float16* h1seq    = (_Float16*)(ws + 4227072);    // 33554432 B (512 x 64KB, write-once)
  _Float16* h2seq    = (_Float16*)(ws + 37781504);   // 33554432 B (512 x 64KB, write-once)
  float*    xp1ring  = (float*)(ws + 71335936);      // 2097152 B (4 x 512KB)
  float*    xp0ring  = (float*)(ws + 73433088);      // 8388608 B (16 x 512KB)
  _Float16* x0       = (_Float16*)(ws + 81821696);   // 20971520 B [512][64][320]
  float*    bias0    = (float*)(ws + 102793216);     // 8192 B (r,z,nx,nh)
  float*    bias1    = (float*)(ws + 102801408);     // 8192 B
  // total ws use: 102809600 B

  hipMemsetAsync(ws, 0, 32768, stream);  // flags only (pooledPart fully overwritten)
  prep_x0<<<4096, 256, 0, stream>>>(texts, emb, x0);
  prep_b<<<2, 256, 0, stream>>>(bih0, bhh0, bih1, bhh1, bias0, bias1);
  gru_persistent<<<128, 256, 0, stream>>>(x0, Wih0, Whh0, Wih1, Whh1, bias0, bias1,
                                          h1seq, h2seq, xp0ring, xp1ring, pooledPt,
                                          flags0, flagsP0, flagsP1, flags1);
  fc_kernel<<<512, 64, 0, stream>>>(pooledPt, fcW, fcb, out);
}

// Round 16
// 2677.412 us; speedup vs baseline: 1.2448x; 1.2448x over previous
//
#include <hip/hip_runtime.h>

#define T_STEPS 512
#define BB 64
#define EE 300
#define EP 320
#define HH 512
#define HB (BB*HH)        // halves per h slot (65536 B)
#define XPSLOT 524288     // bytes per xp slot: 64 rows * 512 cols * 16B (f32 r,z,n,pad)
#define FS 16             // flag stride in ints (64 B): producer-exclusive cache line

typedef _Float16 f16x8 __attribute__((ext_vector_type(8)));
typedef float f32x4 __attribute__((ext_vector_type(4)));
typedef int i32x4 __attribute__((ext_vector_type(4)));

__device__ __forceinline__ f32x4 mf(f16x8 a, f16x8 b, f32x4 c) {
  return __builtin_amdgcn_mfma_f32_16x16x32_f16(a, b, c, 0, 0, 0);
}

// ---- 3-phase progressive split-K load blocks (write-once h -> PLAIN loads) ----
// Phase A: chunks 0-3 (cols 0-127, producers 0-7) + 4 sc1 xp loads + sc1 probe of
// producers 8-15, ONE drain. Probes ride data drains: zero extra round-trips.
// Flags are monotone, so a stale "ready" probe is still valid when checked later.
__device__ __forceinline__ void load_h4a_xp_probe(i32x4* q, f32x4* xp, int* pb,
    const void* hbase, int hvoff, const void* xbase, const int* vx,
    const int* probe) {
  asm volatile(
    "global_load_dwordx4 %0, %9,  %10\n\t"
    "global_load_dwordx4 %1, %9,  %10 offset:64\n\t"
    "global_load_dwordx4 %2, %9,  %10 offset:128\n\t"
    "global_load_dwordx4 %3, %9,  %10 offset:192\n\t"
    "global_load_dwordx4 %4, %11, %15 sc1\n\t"
    "global_load_dwordx4 %5, %12, %15 sc1\n\t"
    "global_load_dwordx4 %6, %13, %15 sc1\n\t"
    "global_load_dwordx4 %7, %14, %15 sc1\n\t"
    "global_load_dword   %8, %16, off sc1\n\t"
    "s_waitcnt vmcnt(0)"
    : "=v"(q[0]), "=v"(q[1]), "=v"(q[2]), "=v"(q[3]),
      "=v"(xp[0]), "=v"(xp[1]), "=v"(xp[2]), "=v"(xp[3]), "=v"(*pb)
    : "v"(hvoff), "s"(hbase), "v"(vx[0]), "v"(vx[1]), "v"(vx[2]), "v"(vx[3]),
      "s"(xbase), "v"(probe)
    : "memory");
}

// Phase A for P1: chunks 0-3 + probe(8-15), one drain
__device__ __forceinline__ void load_h4a_probe(i32x4* q, int* pb,
    const void* hbase, int hvoff, const int* probe) {
  asm volatile(
    "global_load_dwordx4 %0, %5, %6\n\t"
    "global_load_dwordx4 %1, %5, %6 offset:64\n\t"
    "global_load_dwordx4 %2, %5, %6 offset:128\n\t"
    "global_load_dwordx4 %3, %5, %6 offset:192\n\t"
    "global_load_dword   %4, %7, off sc1\n\t"
    "s_waitcnt vmcnt(0)"
    : "=v"(q[0]), "=v"(q[1]), "=v"(q[2]), "=v"(q[3]), "=v"(*pb)
    : "v"(hvoff), "s"(hbase), "v"(probe) : "memory");
}

// Phase B: chunks 4-7 (cols 128-255, producers 8-15) + probe(16-31), one drain
__device__ __forceinline__ void load_h4b_probe(i32x4* q, int* pc,
    const void* hbase, int hvoff, const int* probe) {
  asm volatile(
    "global_load_dwordx4 %0, %5, %6 offset:256\n\t"
    "global_load_dwordx4 %1, %5, %6 offset:320\n\t"
    "global_load_dwordx4 %2, %5, %6 offset:384\n\t"
    "global_load_dwordx4 %3, %5, %6 offset:448\n\t"
    "global_load_dword   %4, %7, off sc1\n\t"
    "s_waitcnt vmcnt(0)"
    : "=v"(q[0]), "=v"(q[1]), "=v"(q[2]), "=v"(q[3]), "=v"(*pc)
    : "v"(hvoff), "s"(hbase), "v"(probe) : "memory");
}

// Phase C: chunks 8-15 (cols 256-511, producers 16-31), one drain
__device__ __forceinline__ void load_h8c(i32x4* q, const void* hbase, int hvoff) {
  asm volatile(
    "global_load_dwordx4 %0, %8, %9 offset:512\n\t"
    "global_load_dwordx4 %1, %8, %9 offset:576\n\t"
    "global_load_dwordx4 %2, %8, %9 offset:640\n\t"
    "global_load_dwordx4 %3, %8, %9 offset:704\n\t"
    "global_load_dwordx4 %4, %8, %9 offset:768\n\t"
    "global_load_dwordx4 %5, %8, %9 offset:832\n\t"
    "global_load_dwordx4 %6, %8, %9 offset:896\n\t"
    "global_load_dwordx4 %7, %8, %9 offset:960\n\t"
    "s_waitcnt vmcnt(0)"
    : "=v"(q[0]), "=v"(q[1]), "=v"(q[2]), "=v"(q[3]),
      "=v"(q[4]), "=v"(q[5]), "=v"(q[6]), "=v"(q[7])
    : "v"(hvoff), "s"(hbase) : "memory");
}

__device__ __forceinline__ void load_xp4(f32x4* xp, const void* xbase, const int* vx) {
  asm volatile(
    "global_load_dwordx4 %0, %4, %8 sc1\n\t"
    "global_load_dwordx4 %1, %5, %8 sc1\n\t"
    "global_load_dwordx4 %2, %6, %8 sc1\n\t"
    "global_load_dwordx4 %3, %7, %8 sc1\n\t"
    "s_waitcnt vmcnt(0)"
    : "=v"(xp[0]), "=v"(xp[1]), "=v"(xp[2]), "=v"(xp[3])
    : "v"(vx[0]), "v"(vx[1]), "v"(vx[2]), "v"(vx[3]), "s"(xbase) : "memory");
}

// batched x-prefetch: 10 plain cached loads + full drain (x0 is immutable)
__device__ __forceinline__ void loadx10_wait(i32x4* xq, const void* base, int voff) {
  asm volatile(
    "global_load_dwordx4 %0, %10, %11\n\t"
    "global_load_dwordx4 %1, %10, %11 offset:64\n\t"
    "global_load_dwordx4 %2, %10, %11 offset:128\n\t"
    "global_load_dwordx4 %3, %10, %11 offset:192\n\t"
    "global_load_dwordx4 %4, %10, %11 offset:256\n\t"
    "global_load_dwordx4 %5, %10, %11 offset:320\n\t"
    "global_load_dwordx4 %6, %10, %11 offset:384\n\t"
    "global_load_dwordx4 %7, %10, %11 offset:448\n\t"
    "global_load_dwordx4 %8, %10, %11 offset:512\n\t"
    "global_load_dwordx4 %9, %10, %11 offset:576\n\t"
    "s_waitcnt vmcnt(0)"
    : "=v"(xq[0]), "=v"(xq[1]), "=v"(xq[2]), "=v"(xq[3]), "=v"(xq[4]),
      "=v"(xq[5]), "=v"(xq[6]), "=v"(xq[7]), "=v"(xq[8]), "=v"(xq[9])
    : "v"(voff), "s"(base) : "memory");
}

__device__ __forceinline__ f16x8 fragq(i32x4 q) {
  union { i32x4 i; f16x8 v; } x; x.i = q; return x.v;
}

// publish: write-through to MALL (no L2 allocate) so consumers' L2 fills are fresh
__device__ __forceinline__ void st16_mall(void* p, f16x8 v) {
  i32x4 iv;
  __builtin_memcpy(&iv, &v, 16);
  asm volatile("global_store_dwordx4 %0, %1, off sc0 sc1" :: "v"(p), "v"(iv) : "memory");
}
__device__ __forceinline__ void st16f(void* p, f32x4 v) {
  i32x4 iv;
  __builtin_memcpy(&iv, &v, 16);
  asm volatile("global_store_dwordx4 %0, %1, off sc0 sc1" :: "v"(p), "v"(iv) : "memory");
}
__device__ __forceinline__ void st4_dev(int* p, int v) {
  asm volatile("global_store_dword %0, %1, off sc0 sc1" :: "v"(p), "v"(v) : "memory");
}

// leading wait: lanes 0-31 poll the 8 phase-A producer lines (4 dup lanes each),
// lanes 32-63 poll ONE column-matched xp flag (broadcast-coalesced).
__device__ __forceinline__ void wait8_plus1(const int* b8, int t8,
                                            const int* pone, int tone, int slp) {
  const int lane = threadIdx.x & 63;
  const int* p = (lane < 32) ? (b8 + (lane & 7) * FS) : pone;
  const int t = (lane < 32) ? t8 : tone;
  for (;;) {
    int v;
    asm volatile("global_load_dword %0, %1, off sc1\n\ts_waitcnt vmcnt(0)"
                 : "=v"(v) : "v"(p) : "memory");
    if (__all(v >= t)) return;
    for (int i = 0; i < slp; ++i) __builtin_amdgcn_s_sleep(1);
  }
}

// fallback waits when an optimistic probe missed (rare)
__device__ __forceinline__ void wait8(const int* base, int t, int slp) {
  const int* p = base + (threadIdx.x & 7) * FS;
  for (;;) {
    int v;
    asm volatile("global_load_dword %0, %1, off sc1\n\ts_waitcnt vmcnt(0)"
                 : "=v"(v) : "v"(p) : "memory");
    if (__all(v >= t)) return;
    for (int i = 0; i < slp; ++i) __builtin_amdgcn_s_sleep(1);
  }
}
__device__ __forceinline__ void wait16(const int* base, int t, int slp) {
  const int* p = base + (threadIdx.x & 15) * FS;
  for (;;) {
    int v;
    asm volatile("global_load_dword %0, %1, off sc1\n\ts_waitcnt vmcnt(0)"
                 : "=v"(v) : "v"(p) : "memory");
    if (__all(v >= t)) return;
    for (int i = 0; i < slp; ++i) __builtin_amdgcn_s_sleep(1);
  }
}

// single-flag wait (all lanes broadcast-load one address)
__device__ __forceinline__ void wait_one(const int* p, int t, int slp) {
  for (;;) {
    int v;
    asm volatile("global_load_dword %0, %1, off sc1\n\ts_waitcnt vmcnt(0)"
                 : "=v"(v) : "v"(p) : "memory");
    if (__all(v >= t)) return;
    for (int i = 0; i < slp; ++i) __builtin_amdgcn_s_sleep(1);
  }
}

__device__ __forceinline__ float sigf(float x) { return 1.f / (1.f + __expf(-x)); }

struct B3 { f16x8 r, z, n; };
// LDS weight read: [chunk][gate(3)][jj(16)][40 halves] — 40-half jj stride spreads the
// 16 cols across bank windows 4*((5*jj+quad) mod 8): uniform, max 2-way (free).
__device__ __forceinline__ B3 ldsB(const _Float16* wl, int chunk, int jj, int kq) {
  B3 o;
  const _Float16* p = wl + chunk * 1920 + jj * 40 + kq;
  o.r = *(const f16x8*)p;
  o.z = *(const f16x8*)(p + 640);
  o.n = *(const f16x8*)(p + 1280);
  return o;
}

__global__ void prep_x0(const int* __restrict__ texts, const float* __restrict__ emb,
                        _Float16* __restrict__ x0) {
  const size_t N = (size_t)T_STEPS * BB * EP;
  const size_t stride = (size_t)gridDim.x * blockDim.x;
  for (size_t i = (size_t)blockIdx.x * blockDim.x + threadIdx.x; i < N; i += stride) {
    int e = (int)(i % EP);
    size_t tb = i / EP;
    float v = 0.f;
    if (e < EE) v = emb[(size_t)texts[tb] * EE + e];
    x0[i] = (_Float16)v;
  }
}

__global__ void prep_b(const float* __restrict__ bih0, const float* __restrict__ bhh0,
                       const float* __restrict__ bih1, const float* __restrict__ bhh1,
                       float* __restrict__ bias0, float* __restrict__ bias1) {
  int i = blockIdx.x * blockDim.x + threadIdx.x;
  if (i < HH) {
    bias0[i]        = bih0[i] + bhh0[i];
    bias0[512 + i]  = bih0[512 + i] + bhh0[512 + i];
    bias0[1024 + i] = bih0[1024 + i];
    bias0[1536 + i] = bhh0[1024 + i];
    bias1[i]        = bih1[i] + bhh1[i];
    bias1[512 + i]  = bih1[512 + i] + bhh1[512 + i];
    bias1[1024 + i] = bih1[1024 + i];
    bias1[1536 + i] = bhh1[1024 + i];
  }
}

// 128 WGs x 256 threads, 4 roles x 32 WGs; each WG = 4 independent waves, one per
// 16-row batch group. 3-PHASE PROGRESSIVE split-K detect (verified optimum of the
// phase-granularity curve: 2ph-merged=3619, 2ph=2743, 3ph=2592-2648, 4ph=3459):
// wait only producers 0-7 (max8) + xp flag; sets {8-15} and {16-31} probed via
// flag loads riding the previous data drains, checked from registers — tails hide
// behind accumulated load+MFMA cover. h1/h2 WRITE-ONCE (plain cached loads);
// xp rings sc1 with column-matched single-flag deps; pooled partials plain stores.
__global__ __launch_bounds__(256, 1) void gru_persistent(
    const _Float16* __restrict__ x0,
    const float* __restrict__ Wih0, const float* __restrict__ Whh0,
    const float* __restrict__ Wih1, const float* __restrict__ Whh1,
    const float* __restrict__ bias0, const float* __restrict__ bias1,
    _Float16* h1seq, _Float16* h2seq, float* xp0ring, float* xp1ring,
    float* pooledPart, int* flags0, int* flagsP0, int* flagsP1, int* flags1)
{
  const int wg   = blockIdx.x;
  const int role = wg >> 5;          // 0=L0 1=P0 2=P1 3=L1
  const int w    = wg & 31;          // column slice 0..31
  const int jb   = w * 16;           // 16 h-cols per WG
  const int tid  = threadIdx.x;
  const int g    = tid >> 6;         // wave = batch group, rows g*16..+15
  const int lane = tid & 63;
  const int quad = lane >> 4;
  const int l15  = lane & 15;
  const int kq   = quad * 8;
  const int hoff = (g * 16 + l15) * 1024 + quad * 16;  // byte voffset into an h slot

  __shared__ alignas(16) _Float16 wlds[30720];     // 16 chunks x 1920 halves = 60 KiB
  __shared__ alignas(16) _Float16 tile[4][16][16]; // per-wave publish transpose, 2 KiB

  // ---- one-time LDS weight fill (fp32 global -> f16, 40-half jj stride) ----
  {
    const float* Wsrc = (role == 0) ? Whh0 : (role == 1) ? Wih0
                      : (role == 2) ? Wih1 : Whh1;
    const int nch  = (role == 1) ? 10 : 16;
    const int Ksrc = (role == 1) ? EE : HH;
    for (int idx = tid; idx < nch * 192; idx += 256) {
      int q = idx & 3, jj = (idx >> 2) & 15, g3 = (idx >> 6) % 3, ch = idx / 192;
      int row = g3 * 512 + jb + jj;
      _Float16* dst = wlds + ch * 1920 + g3 * 640 + jj * 40 + q * 8;
      int colb = ch * 32 + q * 8;
      #pragma unroll
      for (int e = 0; e < 8; ++e) {
        int col = colb + e;
        dst[e] = (col < Ksrc) ? (_Float16)Wsrc[(size_t)row * Ksrc + col] : (_Float16)0.f;
      }
    }
  }
  __syncthreads();

  // loop-invariant xp voffsets: [row 64][hcol 512][gate pad4] f32 -> row stride 8192 B
  int vx[4];
  #pragma unroll
  for (int rg = 0; rg < 4; ++rg)
    vx[rg] = (g * 16 + quad * 4 + rg) * 8192 + (jb + l15) * 16;

  const int* fg0  = flags0  + g * 32 * FS;   // 32 producers x 64B per group
  const int* fgP0 = flagsP0 + g * 32 * FS;
  const int* fgP1 = flagsP1 + g * 32 * FS;
  const int* fg1  = flags1  + g * 32 * FS;

  if (role == 0) {            // ---------------- L0: h1 recurrence ----------------
    const int j = jb + l15;
    const float br = bias0[j], bz = bias0[512 + j];
    const float bnx = bias0[1024 + j], bnh = bias0[1536 + j];
    int* myf = flags0 + (g * 32 + w) * FS;
    const int* pP0w = fgP0 + w * FS;                 // single column-matched P0 flag
    const int* prbB = fg0 + (8 + (l15 & 7)) * FS;    // producers 8-15 probe addr
    const int* prbC = fg0 + (16 + l15) * FS;         // producers 16-31 probe addr
    float hprev[4] = {0.f, 0.f, 0.f, 0.f};
    _Float16 (*tc)[16] = tile[g];
    for (int s = 0; s < T_STEPS; ++s) {
      // phase-A h dep (producers 0-7) + xp dep (P0 WG w only)
      wait8_plus1(fg0, s, pP0w, s + 1, 1);
      f32x4 hR = {0.f,0.f,0.f,0.f}, hZ = {0.f,0.f,0.f,0.f}, hN = {0.f,0.f,0.f,0.f};
      f32x4 xp[4];
      const void* xb = (const char*)xp0ring + (size_t)(s & 15) * XPSLOT;
      if (s >= 1) {
        const void* hb = h1seq + (size_t)(s - 1) * HB;
        i32x4 qa[4]; int pb;
        load_h4a_xp_probe(qa, xp, &pb, hb, hoff, xb, vx, prbB);
        #pragma unroll
        for (int c = 0; c < 4; ++c) {
          f16x8 a = fragq(qa[c]);
          B3 bb = ldsB(wlds, c, l15, kq);
          hR = mf(a, bb.r, hR); hZ = mf(a, bb.z, hZ); hN = mf(a, bb.n, hN);
        }
        if (!__all(pb >= s)) wait8(fg0 + 8 * FS, s, 1);
        i32x4 qb[4]; int pc;
        load_h4b_probe(qb, &pc, hb, hoff, prbC);
        #pragma unroll
        for (int c = 0; c < 4; ++c) {
          f16x8 a = fragq(qb[c]);
          B3 bb = ldsB(wlds, 4 + c, l15, kq);
          hR = mf(a, bb.r, hR); hZ = mf(a, bb.z, hZ); hN = mf(a, bb.n, hN);
        }
        if (!__all(pc >= s)) wait16(fg0 + 16 * FS, s, 1);
        i32x4 qc[8];
        load_h8c(qc, hb, hoff);
        #pragma unroll 4
        for (int c = 0; c < 8; ++c) {
          f16x8 a = fragq(qc[c]);
          B3 bb = ldsB(wlds, 8 + c, l15, kq);
          hR = mf(a, bb.r, hR); hZ = mf(a, bb.z, hZ); hN = mf(a, bb.n, hN);
        }
      } else {
        load_xp4(xp, xb, vx);
      }
      #pragma unroll
      for (int rg = 0; rg < 4; ++rg) {
        float r = sigf(xp[rg][0] + hR[rg] + br);
        float z = sigf(xp[rg][1] + hZ[rg] + bz);
        float n = tanhf(xp[rg][2] + bnx + r * (hN[rg] + bnh));
        float hnew = (1.f - z) * n + z * hprev[rg];
        hprev[rg] = hnew;
        tc[quad * 4 + rg][l15] = (_Float16)hnew;
      }
      if (lane < 32) {                      // 16 rows x 32B per wave
        int row = lane & 15, hb2 = lane >> 4;
        f16x8 v = *(const f16x8*)&tc[row][hb2 * 8];
        st16_mall(h1seq + (size_t)s * HB
                  + (size_t)(g * 16 + row) * HH + jb + hb2 * 8, v);
      }
      __builtin_amdgcn_s_waitcnt(0);
      if (lane == 0) st4_dev(myf, s + 1);
    }
  } else if (role == 1) {     // ---------------- P0: x projection (ahead) ----------------
    int* myf = flagsP0 + (g * 32 + w) * FS;
    const int* pL0w = fg0 + w * FS;            // only L0 WG w consumes our slice
    const int xoff = (g * 16 + l15) * 640 + quad * 16;
    for (int t = 0; t < T_STEPS; ++t) {
      wait_one(pL0w, t - 15, 8);               // ring throttle — slack, slow sampling
      i32x4 xq[10];
      loadx10_wait(xq, x0 + (size_t)t * BB * EP, xoff);
      f32x4 aR = {0.f,0.f,0.f,0.f}, aZ = {0.f,0.f,0.f,0.f}, aN = {0.f,0.f,0.f,0.f};
      #pragma unroll 5
      for (int c = 0; c < 10; ++c) {
        f16x8 a = fragq(xq[c]);
        B3 bb = ldsB(wlds, c, l15, kq);
        aR = mf(a, bb.r, aR); aZ = mf(a, bb.z, aZ); aN = mf(a, bb.n, aN);
      }
      char* xb = (char*)xp0ring + (size_t)(t & 15) * XPSLOT;
      #pragma unroll
      for (int rg = 0; rg < 4; ++rg) {
        f32x4 v = {aR[rg], aZ[rg], aN[rg], 0.f};
        st16f(xb + vx[rg], v);
      }
      __builtin_amdgcn_s_waitcnt(0);
      if (lane == 0) st4_dev(myf, t + 1);
    }
  } else if (role == 2) {     // ---------------- P1: h1 -> xp1 projection ----------------
    int* myf = flagsP1 + (g * 32 + w) * FS;
    const int* pL1w = fg1 + w * FS;            // only L1 WG w consumes our slice
    const int* prbB = fg0 + (8 + (l15 & 7)) * FS;
    const int* prbC = fg0 + (16 + l15) * FS;
    for (int t = 0; t < T_STEPS; ++t) {
      // phase-A of h1[t] (producers 0-7 >= t+1); ring throttle single L1 flag
      wait8_plus1(fg0, t + 1, pL1w, t - 3, 1);
      const void* hb = h1seq + (size_t)t * HB;
      i32x4 qa[4]; int pb;
      load_h4a_probe(qa, &pb, hb, hoff, prbB);
      f32x4 aR = {0.f,0.f,0.f,0.f}, aZ = {0.f,0.f,0.f,0.f}, aN = {0.f,0.f,0.f,0.f};
      #pragma unroll
      for (int c = 0; c < 4; ++c) {
        f16x8 a = fragq(qa[c]);
        B3 bb = ldsB(wlds, c, l15, kq);
        aR = mf(a, bb.r, aR); aZ = mf(a, bb.z, aZ); aN = mf(a, bb.n, aN);
      }
      if (!__all(pb >= t + 1)) wait8(fg0 + 8 * FS, t + 1, 1);
      i32x4 qb[4]; int pc;
      load_h4b_probe(qb, &pc, hb, hoff, prbC);
      #pragma unroll
      for (int c = 0; c < 4; ++c) {
        f16x8 a = fragq(qb[c]);
        B3 bb = ldsB(wlds, 4 + c, l15, kq);
        aR = mf(a, bb.r, aR); aZ = mf(a, bb.z, aZ); aN = mf(a, bb.n, aN);
      }
      if (!__all(pc >= t + 1)) wait16(fg0 + 16 * FS, t + 1, 1);
      i32x4 qc[8];
      load_h8c(qc, hb, hoff);
      #pragma unroll 4
      for (int c = 0; c < 8; ++c) {
        f16x8 a = fragq(qc[c]);
        B3 bb = ldsB(wlds, 8 + c, l15, kq);
        aR = mf(a, bb.r, aR); aZ = mf(a, bb.z, aZ); aN = mf(a, bb.n, aN);
      }
      char* xb = (char*)xp1ring + (size_t)(t & 3) * XPSLOT;
      #pragma unroll
      for (int rg = 0; rg < 4; ++rg) {
        f32x4 v = {aR[rg], aZ[rg], aN[rg], 0.f};
        st16f(xb + vx[rg], v);
      }
      __builtin_amdgcn_s_waitcnt(0);
      if (lane == 0) st4_dev(myf, t + 1);
    }
  } else {                    // ---------------- L1: h2 recurrence ----------------
    const int j = jb + l15;
    const float br = bias1[j], bz = bias1[512 + j];
    const float bnx = bias1[1024 + j], bnh = bias1[1536 + j];
    int* myf = flags1 + (g * 32 + w) * FS;
    const int* pP1w = fgP1 + w * FS;           // single column-matched P1 flag
    const int* prbB = fg1 + (8 + (l15 & 7)) * FS;
    const int* prbC = fg1 + (16 + l15) * FS;
    float* ppB = pooledPart + ((size_t)g * T_STEPS) * HH + jb;
    float hprev[4] = {0.f, 0.f, 0.f, 0.f};
    _Float16 (*tc)[16] = tile[g];
    for (int t = 0; t < T_STEPS; ++t) {
      // phase-A h dep (producers 0-7 >= t) + xp dep (P1 WG w only >= t+1)
      wait8_plus1(fg1, t, pP1w, t + 1, 1);
      f32x4 hR = {0.f,0.f,0.f,0.f}, hZ = {0.f,0.f,0.f,0.f}, hN = {0.f,0.f,0.f,0.f};
      f32x4 xp[4];
      const void* xb = (const char*)xp1ring + (size_t)(t & 3) * XPSLOT;
      if (t >= 1) {
        const void* hb = h2seq + (size_t)(t - 1) * HB;
        i32x4 qa[4]; int pb;
        load_h4a_xp_probe(qa, xp, &pb, hb, hoff, xb, vx, prbB);
        #pragma unroll
        for (int c = 0; c < 4; ++c) {
          f16x8 a = fragq(qa[c]);
          B3 bb = ldsB(wlds, c, l15, kq);
          hR = mf(a, bb.r, hR); hZ = mf(a, bb.z, hZ); hN = mf(a, bb.n, hN);
        }
        if (!__all(pb >= t)) wait8(fg1 + 8 * FS, t, 1);
        i32x4 qb[4]; int pc;
        load_h4b_probe(qb, &pc, hb, hoff, prbC);
        #pragma unroll
        for (int c = 0; c < 4; ++c) {
          f16x8 a = fragq(qb[c]);
          B3 bb = ldsB(wlds, 4 + c, l15, kq);
          hR = mf(a, bb.r, hR); hZ = mf(a, bb.z, hZ); hN = mf(a, bb.n, hN);
        }
        if (!__all(pc >= t)) wait16(fg1 + 16 * FS, t, 1);
        i32x4 qc[8];
        load_h8c(qc, hb, hoff);
        #pragma unroll 4
        for (int c = 0; c < 8; ++c) {
          f16x8 a = fragq(qc[c]);
          B3 bb = ldsB(wlds, 8 + c, l15, kq);
          hR = mf(a, bb.r, hR); hZ = mf(a, bb.z, hZ); hN = mf(a, bb.n, hN);
        }
      } else {
        load_xp4(xp, xb, vx);
      }
      #pragma unroll
      for (int rg = 0; rg < 4; ++rg) {
        float r = sigf(xp[rg][0] + hR[rg] + br);
        float z = sigf(xp[rg][1] + hZ[rg] + bz);
        float n = tanhf(xp[rg][2] + bnx + r * (hN[rg] + bnh));
        float hnew = (1.f - z) * n + z * hprev[rg];
        hprev[rg] = hnew;
        tc[quad * 4 + rg][l15] = (_Float16)hnew;
      }
      if (lane < 32) {
        int row = lane & 15, hb2 = lane >> 4;
        f16x8 v = *(const f16x8*)&tc[row][hb2 * 8];
        st16_mall(h2seq + (size_t)t * HB
                  + (size_t)(g * 16 + row) * HH + jb + hb2 * 8, v);
      }
      __builtin_amdgcn_s_waitcnt(0);
      if (lane == 0) st4_dev(myf, t + 1);
      // tail (off the flag path): per-group pooled partial, PLAIN store (write-once)
      if (lane < 16) {
        float sum = 0.f;
        #pragma unroll
        for (int r = 0; r < 16; ++r) sum += (float)tc[r][lane];
        ppB[(size_t)t * HH + lane] = sum;
      }
    }
  }
}

__global__ void fc_kernel(const float* __restrict__ pooledPart,
                          const float* __restrict__ fcW,
                          const float* __restrict__ fcb, float* __restrict__ out) {
  const int t = blockIdx.x;
  const int lane = threadIdx.x;  // 64 = one wave
  const size_t GS = (size_t)T_STEPS * HH;   // per-group partial stride
  float a0 = 0.f, a1 = 0.f, a2 = 0.f, a3 = 0.f, a4 = 0.f;
  for (int jj = lane; jj < HH; jj += 64) {
    size_t idx = (size_t)t * HH + jj;
    float p = pooledPart[idx] + pooledPart[GS + idx]
            + pooledPart[2 * GS + idx] + pooledPart[3 * GS + idx];
    a0 += p * fcW[jj];
    a1 += p * fcW[512 + jj];
    a2 += p * fcW[1024 + jj];
    a3 += p * fcW[1536 + jj];
    a4 += p * fcW[2048 + jj];
  }
  #pragma unroll
  for (int off = 32; off > 0; off >>= 1) {
    a0 += __shfl_down(a0, off, 64);
    a1 += __shfl_down(a1, off, 64);
    a2 += __shfl_down(a2, off, 64);
    a3 += __shfl_down(a3, off, 64);
    a4 += __shfl_down(a4, off, 64);
  }
  if (lane == 0) {
    const float sc = 1.f / 64.f;
    out[t * 5 + 0] = a0 * sc + fcb[0];
    out[t * 5 + 1] = a1 * sc + fcb[1];
    out[t * 5 + 2] = a2 * sc + fcb[2];
    out[t * 5 + 3] = a3 * sc + fcb[3];
    out[t * 5 + 4] = a4 * sc + fcb[4];
  }
}

extern "C" void kernel_launch(void* const* d_in, const int* in_sizes, int n_in,
                              void* d_out, int out_size, void* d_ws, size_t ws_size,
                              hipStream_t stream) {
  const int*   texts = (const int*)  d_in[0];
  const float* emb   = (const float*)d_in[1];
  const float* Wih0  = (const float*)d_in[2];
  const float* Whh0  = (const float*)d_in[3];
  const float* bih0  = (const float*)d_in[4];
  const float* bhh0  = (const float*)d_in[5];
  const float* Wih1  = (const float*)d_in[6];
  const float* Whh1  = (const float*)d_in[7];
  const float* bih1  = (const float*)d_in[8];
  const float* bhh1  = (const float*)d_in[9];
  const float* fcW   = (const float*)d_in[10];
  const float* fcb   = (const float*)d_in[11];
  float* out = (float*)d_out;

  char* ws = (char*)d_ws;
  int*      flags0   = (int*)ws;                     // 8192 B (4 grp x 32 x 64B)
  int*      flagsP0  = (int*)(ws + 8192);            // 8192 B
  int*      flagsP1  = (int*)(ws + 16384);           // 8192 B
  int*      flags1   = (int*)(ws + 24576);           // 8192 B
  float*    pooledPt = (float*)(ws + 32768);         // 4194304 B [4][512][512] f32
  _Float16* h1seq    = (_Float16*)(ws + 4227072);    // 33554432 B (512 x 64KB, write-once)
  _Float16* h2seq    = (_Float16*)(ws + 37781504);   // 33554432 B (512 x 64KB, write-once)
  float*    xp1ring  = (float*)(ws + 71335936);      // 2097152 B (4 x 512KB)
  float*    xp0ring  = (float*)(ws + 73433088);      // 8388608 B (16 x 512KB)
  _Float16* x0       = (_Float16*)(ws + 81821696);   // 20971520 B [512][64][320]
  float*    bias0    = (float*)(ws + 102793216);     // 8192 B (r,z,nx,nh)
  float*    bias1    = (float*)(ws + 102801408);     // 8192 B
  // total ws use: 102809600 B

  hipMemsetAsync(ws, 0, 32768, stream);  // flags only (pooledPart fully overwritten)
  prep_x0<<<4096, 256, 0, stream>>>(texts, emb, x0);
  prep_b<<<2, 256, 0, stream>>>(bih0, bhh0, bih1, bhh1, bias0, bias1);
  gru_persistent<<<128, 256, 0, stream>>>(x0, Wih0, Whh0, Wih1, Whh1, bias0, bias1,
                                          h1seq, h2seq, xp0ring, xp1ring, pooledPt,
                                          flags0, flagsP0, flagsP1, flags1);
  fc_kernel<<<512, 64, 0, stream>>>(pooledPt, fcW, fcb, out);
}